// Round 15
// baseline (102.412 us; speedup 1.0000x reference)
//
#include <hip/hip_runtime.h>

// Problem constants: features [C=32, N], coords [N,3]=(b,h,w),
// output [B=64, C=32, NH=64, NW=256] float32.
#define CC 32
#define BB 64
#define NHH 64
#define NWW 256
#define PLANE (NHH * NWW)        // 16384 cells per batch
#define BSTRIDE (CC * PLANE)     // 524288 floats per batch in out
#define NCELLS (BB * PLANE)      // 1048576 total cells
#define LROW 260                 // LDS row stride (256 data dwords + 4 pad)

typedef float f32x4 __attribute__((ext_vector_type(4)));  // builtin-legal vector

// ---------- Fallback (round-1) direct scatter ----------
__global__ void pss_scatter_direct(const float* __restrict__ features,
                                   const int* __restrict__ coords,
                                   float* __restrict__ out, int N) {
    int n = blockIdx.x * blockDim.x + threadIdx.x;
    if (n >= N) return;
    int b = coords[3 * n + 0];
    int h = coords[3 * n + 1];
    int w = coords[3 * n + 2];
    int base = b * BSTRIDE + h * NWW + w;
#pragma unroll
    for (int c = 0; c < CC; ++c)
        out[base + c * PLANE] = features[c * N + n];
}

// ---------- K-1: zero invmap ----------
__global__ __launch_bounds__(256) void pss_zero(int4* __restrict__ p, int n4) {
    int i = blockIdx.x * blockDim.x + threadIdx.x;
    if (i < n4) p[i] = make_int4(0, 0, 0, 0);
}

// ---------- K0: invmap scatter (tiny): invmap[cell] = n+1 ----------
__global__ void pss_invmap(const int* __restrict__ coords,
                           int* __restrict__ invmap, int N) {
    int n = blockIdx.x * blockDim.x + threadIdx.x;
    if (n >= N) return;
    int b = coords[3 * n + 0];
    int h = coords[3 * n + 1];
    int w = coords[3 * n + 2];
    invmap[b * PLANE + h * NWW + w] = n + 1;
}

// ---------- K1: LINEAR-READ block transpose features [C][N] -> featT [N][C] --
// The one factor changed vs r14: the read side is now ONE 1KB-contiguous
// chunk per instruction (whole channel-row segments), instead of 32
// fine-grained 256B streams live simultaneously per wave. Every prior
// transpose variant (r2/r3/r4/r6/r11/r13/r14) shared the 32-stream read and
// all plateaued at 2.5-3.5 TB/s; the only fast readers (gather: L3) and
// writers (fill, featT stores: single coarse stream) avoid it.
//   Load : wave w, instr r: row c=8w+r, lane l reads float4 at n0+4l
//          -> 1KB contiguous per instruction (16-line burst), 8 instrs/wave.
//   LDS  : [32][260] block tile (pad 4 dwords; read conflicts <=4-way,
//          negligible - LDS is ~69 TB/s, not the wall).
//   Store: flat float4 idx = t + 256j -> lanes contiguous 1KB/instr,
//          4KB/instr per block, sequential in n (proven pattern).
__global__ __launch_bounds__(256) void pss_transpose_lin(
        const float* __restrict__ features, float* __restrict__ featT, int N) {
    __shared__ float lds[CC * LROW];  // 32 * 260 * 4B = 33280 B

    int t = threadIdx.x;
    int lane = t & 63;
    int w = t >> 6;
    int n0 = blockIdx.x * 256;

    // Load phase: wave w owns rows c = 8w .. 8w+7.
#pragma unroll
    for (int r = 0; r < 8; ++r) {
        int c = 8 * w + r;
        int n = n0 + 4 * lane;
        f32x4 v = (f32x4){0.f, 0.f, 0.f, 0.f};
        if (n < N)  // N % 4 == 0, so n<N implies n+3<N
            v = __builtin_nontemporal_load(
                (const f32x4*)&features[(size_t)c * N + n]);
        *(f32x4*)&lds[c * LROW + 4 * lane] = v;
    }

    __syncthreads();

    // Store phase: transposed read + linear float4 store.
    float4* dstv = (float4*)featT;
#pragma unroll
    for (int j = 0; j < 8; ++j) {
        int idx = t + 256 * j;          // flat float4 index within tile
        int nl = idx >> 3;              // local n (0..255)
        int q = idx & 7;                // channel quad (0..7)
        if (n0 + nl < N) {
            float4 v;
            v.x = lds[(4 * q + 0) * LROW + nl];
            v.y = lds[(4 * q + 1) * LROW + nl];
            v.z = lds[(4 * q + 2) * LROW + nl];
            v.w = lds[(4 * q + 3) * LROW + nl];
            // normal store (NOT nontemporal): featT must stay L3-resident
            // for the gather's random row reads.
            dstv[(size_t)n0 * 8 + idx] = v;
        }
    }
}

// ---------- K2: gather featT rows per cell, emit out coalesced ----------
// featT rows random but L3-resident. out stores nontemporal (write-once
// stream; don't evict featT).
__global__ __launch_bounds__(256) void pss_gather_emit(
        const float* __restrict__ featT, const int* __restrict__ invmap,
        float* __restrict__ out) {
    __shared__ float lds[NWW * (CC + 1)];  // 256 * 33 floats

    int row = blockIdx.x;          // 0 .. B*NH-1  (row = b*NHH + h)
    int b = row / NHH;
    int h = row % NHH;
    int t = threadIdx.x;           // 0..255 = w

    int inv = invmap[(size_t)row * NWW + t];  // coalesced 1KB per block

    if (inv > 0) {
        const float4* src = (const float4*)(featT + (size_t)(inv - 1) * CC);
#pragma unroll
        for (int k = 0; k < CC / 4; ++k) {
            float4 v = src[k];
            lds[t * (CC + 1) + 4 * k + 0] = v.x;
            lds[t * (CC + 1) + 4 * k + 1] = v.y;
            lds[t * (CC + 1) + 4 * k + 2] = v.z;
            lds[t * (CC + 1) + 4 * k + 3] = v.w;
        }
    } else {
#pragma unroll
        for (int k = 0; k < CC; ++k)
            lds[t * (CC + 1) + k] = 0.0f;
    }

    __syncthreads();

    size_t obase = (size_t)b * BSTRIDE + (size_t)h * NWW + t;
#pragma unroll
    for (int c = 0; c < CC; ++c) {
        float v = lds[t * (CC + 1) + c];  // bank (t+c)%32 -> conflict-free
        __builtin_nontemporal_store(v, &out[obase + (size_t)c * PLANE]);
    }
}

extern "C" void kernel_launch(void* const* d_in, const int* in_sizes, int n_in,
                              void* d_out, int out_size, void* d_ws, size_t ws_size,
                              hipStream_t stream) {
    const float* features = (const float*)d_in[0];
    const int* coords = (const int*)d_in[1];
    float* out = (float*)d_out;
    const int N = in_sizes[1] / 3;

    const size_t invmap_bytes = (size_t)NCELLS * sizeof(int);       // 4 MiB
    const size_t featT_bytes = (size_t)N * CC * sizeof(float);      // ~115 MB

    if (ws_size < invmap_bytes + featT_bytes) {
        // Fallback: direct scatter (correct, slower).
        (void)hipMemsetAsync(d_out, 0, (size_t)out_size * sizeof(float), stream);
        int blocks = (N + 255) / 256;
        pss_scatter_direct<<<blocks, 256, 0, stream>>>(features, coords, out, N);
        return;
    }

    int* invmap = (int*)d_ws;
    float* featT = (float*)((char*)d_ws + invmap_bytes);

    // Zero invmap (0 == empty cell).
    pss_zero<<<(NCELLS / 4 + 255) / 256, 256, 0, stream>>>((int4*)invmap,
                                                           NCELLS / 4);

    pss_invmap<<<(N + 255) / 256, 256, 0, stream>>>(coords, invmap, N);

    int tiles = (N + 255) / 256;
    pss_transpose_lin<<<tiles, 256, 0, stream>>>(features, featT, N);

    pss_gather_emit<<<BB * NHH, 256, 0, stream>>>(featT, invmap, out);
}